// Round 17
// baseline (207.980 us; speedup 1.0000x reference)
//
#include <hip/hip_runtime.h>
#include <hip/hip_bf16.h>

// R17 = R16 + kt-pipelined compute (T15): QK(kt+1) computed inside round kt,
// right after the softmax that frees its score regs -> every MFMA cluster has
// independent softmax VALU to hide under (R13/R16: QK sat exposed after the
// barrier; phase-locked waves alternated MFMA/VALU phases). s_A/s_B reused ->
// register count unchanged (~96 incl AGPR, 4 waves/SIMD preserved).
// Pt 32 rows/wave (P0,P1 both live) -> LDS 80KB = exactly 2 blocks/CU.
// Sync per round: barrier(safety) -> stage(kt+2) -> vmcnt(2) -> barrier(vis).
// 8-wave blocks, exp2-native fixed-max softmax (scores bounded -> m=0, exact).
// bf16 MFMA flash attention, pre-swizzled K/V tile images in ws.
// B=4 H=16 S=2048 D=64, f32 in/out, multiplicative mask.

typedef __attribute__((ext_vector_type(4))) float  f32x4;
typedef __attribute__((ext_vector_type(8))) short  short8;
typedef __attribute__((ext_vector_type(4))) short  short4v;

constexpr int S = 2048, D = 64;
constexpr int NBH = 64;
constexpr int QBLK = 256, KT = 64;
constexpr int NQT = S / QBLK;      // 8
constexpr int NKT = S / KT;        // 32
constexpr float SCALE = 0.125f * 1.44269504088896340736f;  // (1/T)*log2(e)
constexpr size_t TILE_SH = (size_t)KT * D;                 // 4096 shorts (8KB) per tile
constexpr size_t IMG_SH  = (size_t)NBH * NKT * TILE_SH;
constexpr size_t WS_NEED = 2 * IMG_SH * sizeof(short);     // 33.55 MB

__device__ inline unsigned short bfb(float x) {
    union { __hip_bfloat16 h; unsigned short u; } cv;
    cv.h = __float2bfloat16(x);
    return cv.u;
}

__device__ inline float fexp2(float x) {   // native v_exp_f32 (exp2)
#if __has_builtin(__builtin_amdgcn_exp2f)
    return __builtin_amdgcn_exp2f(x);
#else
    return __expf(x * 0.6931471805599453f);
#endif
}

__device__ inline void gload16(const short* g, short* l) {
    auto gp = (const __attribute__((address_space(1))) int*)g;
    auto lp = (__attribute__((address_space(3))) int*)l;
    __builtin_amdgcn_global_load_lds(gp, lp, 16, 0, 0);
}

// ---- merged pre-pass (64-key tiles, 64-wide rows) — unchanged.
// blocks [0, NBH*NKT):        K -> swizzled bf16 tile image [key][d^8*(key&7)]
// blocks [NBH*NKT, 2*NBH*NKT): V -> transposed swizzled image [d][key^8*(d&7)]
__global__ __launch_bounds__(256)
void conv_kv(const float* __restrict__ K, const float* __restrict__ V,
             short* __restrict__ Kimg, short* __restrict__ Vimg) {
    const int t = threadIdx.x;
    const int nt = NBH * NKT;
    if (blockIdx.x < nt) {
        const float* src = K + (size_t)blockIdx.x * TILE_SH;
        short* dst = Kimg + (size_t)blockIdx.x * TILE_SH;
        const int row = t >> 2, c16 = (t & 3) * 16;
        const int swz = (row & 7) << 3;
        float4 f0 = *reinterpret_cast<const float4*>(src + row * D + c16 + 0);
        float4 f1 = *reinterpret_cast<const float4*>(src + row * D + c16 + 4);
        float4 f2 = *reinterpret_cast<const float4*>(src + row * D + c16 + 8);
        float4 f3 = *reinterpret_cast<const float4*>(src + row * D + c16 + 12);
        short8 a, b;
        a[0]=bfb(f0.x); a[1]=bfb(f0.y); a[2]=bfb(f0.z); a[3]=bfb(f0.w);
        a[4]=bfb(f1.x); a[5]=bfb(f1.y); a[6]=bfb(f1.z); a[7]=bfb(f1.w);
        b[0]=bfb(f2.x); b[1]=bfb(f2.y); b[2]=bfb(f2.z); b[3]=bfb(f2.w);
        b[4]=bfb(f3.x); b[5]=bfb(f3.y); b[6]=bfb(f3.z); b[7]=bfb(f3.w);
        *reinterpret_cast<short8*>(dst + row * 64 + (c16 ^ swz)) = a;
        *reinterpret_cast<short8*>(dst + row * 64 + ((c16 + 8) ^ swz)) = b;
    } else {
        __shared__ float tl[64][65];
        const int blk = blockIdx.x - nt;
        const float* src = V + (size_t)blk * TILE_SH;
        short* dst = Vimg + (size_t)blk * TILE_SH;
        const int row = t >> 2, c16 = (t & 3) * 16;
        {
            float4 f0 = *reinterpret_cast<const float4*>(src + row * D + c16 + 0);
            float4 f1 = *reinterpret_cast<const float4*>(src + row * D + c16 + 4);
            float4 f2 = *reinterpret_cast<const float4*>(src + row * D + c16 + 8);
            float4 f3 = *reinterpret_cast<const float4*>(src + row * D + c16 + 12);
            tl[row][c16+0]=f0.x;  tl[row][c16+1]=f0.y;  tl[row][c16+2]=f0.z;  tl[row][c16+3]=f0.w;
            tl[row][c16+4]=f1.x;  tl[row][c16+5]=f1.y;  tl[row][c16+6]=f1.z;  tl[row][c16+7]=f1.w;
            tl[row][c16+8]=f2.x;  tl[row][c16+9]=f2.y;  tl[row][c16+10]=f2.z; tl[row][c16+11]=f2.w;
            tl[row][c16+12]=f3.x; tl[row][c16+13]=f3.y; tl[row][c16+14]=f3.z; tl[row][c16+15]=f3.w;
        }
        __syncthreads();
        const int d = t >> 2, k16 = (t & 3) * 16;
        const int swz = (d & 7) << 3;
        float vv[16];
#pragma unroll
        for (int j = 0; j < 16; ++j) vv[j] = tl[k16 + j][d];
        short8 a, b;
#pragma unroll
        for (int j = 0; j < 8; ++j) { a[j] = bfb(vv[j]); b[j] = bfb(vv[j + 8]); }
        *reinterpret_cast<short8*>(dst + d * 64 + (k16 ^ swz)) = a;
        *reinterpret_cast<short8*>(dst + d * 64 + ((k16 + 8) ^ swz)) = b;
    }
}

// ---- main attention kernel: 8 waves x 32 q-rows (2 rowtiles) each
__global__ __launch_bounds__(512)
void attn_img(const float* __restrict__ Q, const float* __restrict__ M,
              const short* __restrict__ Kimg, const short* __restrict__ Vimg,
              float* __restrict__ O)
{
    __shared__ short Kb[3][4096];     // 24 KB triple buffer
    __shared__ short Vb[3][4096];     // 24 KB
    __shared__ short Pt[8][32][64];   // 32 KB: both rowtiles' P per wave
    // total 80 KB -> exactly 2 blocks/CU

    const int tid  = threadIdx.x;
    const int w    = tid >> 6;        // 0..7
    const int lane = tid & 63;
    const int g    = lane >> 4;
    const int c    = lane & 15;
    const int swz8 = (c & 7) << 3;    // fragment-read swizzle (row%8 == c%8)

    const int bid = blockIdx.x;
    const int bh  = bid >> 3;         // consecutive bids share bh -> L2 reuse
    const int qt  = bid & 7;
    const int qw  = qt * QBLK + w * 32;

    const size_t bhS = (size_t)bh * S;
    const size_t bhT = (size_t)bh * NKT;

    // ---- Q fragments (B operand): bQ[rt][kk], row = qw+rt*16+c, k = d
    short8 bQ[2][2];
#pragma unroll
    for (int rt = 0; rt < 2; ++rt) {
        const float* qp = Q + (bhS + qw + rt * 16 + c) * D;
#pragma unroll
        for (int kk = 0; kk < 2; ++kk) {
            const float* q8 = qp + kk * 32 + g * 8;
            float4 a = *reinterpret_cast<const float4*>(q8);
            float4 b = *reinterpret_cast<const float4*>(q8 + 4);
            short8 r;
            r[0] = bfb(a.x * SCALE); r[1] = bfb(a.y * SCALE);
            r[2] = bfb(a.z * SCALE); r[3] = bfb(a.w * SCALE);
            r[4] = bfb(b.x * SCALE); r[5] = bfb(b.y * SCALE);
            r[6] = bfb(b.z * SCALE); r[7] = bfb(b.w * SCALE);
            bQ[rt][kk] = r;
        }
    }

    const float* mrow0 = M + (size_t)(qw + c) * S;
    const float* mrow1 = M + (size_t)(qw + 16 + c) * S;

    f32x4 acc[2][4] = {};             // [rt][d-ntile] (AGPRs)
    float lR[2] = {0.f, 0.f};         // per-lane partial denominator

    // stage: 512 threads x 16B = full 8KB tile in ONE pass per tensor
    auto stage = [&](int buf, int kt) {
        const short* ks = Kimg + (bhT + kt) * TILE_SH + tid * 8;
        const short* vs = Vimg + (bhT + kt) * TILE_SH + tid * 8;
        gload16(ks, &Kb[buf][tid * 8]);
        gload16(vs, &Vb[buf][tid * 8]);
    };

    // QK of one rowtile from tile Kt (zeroes then accumulates into s)
    auto qk = [&](const short* Kt, const short8 (&bq)[2], f32x4 (&s)[4]) {
#pragma unroll
        for (int n = 0; n < 4; ++n) s[n] = (f32x4){0.f, 0.f, 0.f, 0.f};
#pragma unroll
        for (int kk = 0; kk < 2; ++kk) {
            short8 aK[4];
#pragma unroll
            for (int n = 0; n < 4; ++n)
                aK[n] = *reinterpret_cast<const short8*>(
                    &Kt[(n * 16 + c) * 64 + ((kk * 32 + g * 8) ^ swz8)]);
            __builtin_amdgcn_s_setprio(1);
#pragma unroll
            for (int n = 0; n < 4; ++n)
                s[n] = __builtin_amdgcn_mfma_f32_16x16x32_bf16(aK[n], bq[kk], s[n], 0, 0, 0);
            __builtin_amdgcn_s_setprio(0);
        }
    };

    // mask*exp2 (fixed max 0, exact) -> P rows rt*16+c, partial denom
    auto softmax = [&](int rt, const float* mrow, int k0, f32x4 (&s)[4]) {
        float lp = 0.f;
#pragma unroll
        for (int n = 0; n < 4; ++n) {
            float4 mk = *reinterpret_cast<const float4*>(mrow + k0 + n * 16 + g * 4);
            float e0 = fexp2(s[n][0] * mk.x);
            float e1 = fexp2(s[n][1] * mk.y);
            float e2 = fexp2(s[n][2] * mk.z);
            float e3 = fexp2(s[n][3] * mk.w);
            lp += (e0 + e1) + (e2 + e3);
            short4v pk;
            pk[0] = bfb(e0); pk[1] = bfb(e1); pk[2] = bfb(e2); pk[3] = bfb(e3);
            *reinterpret_cast<short4v*>(
                &Pt[w][rt * 16 + c][(n * 16 + g * 4) ^ swz8]) = pk;
        }
        lR[rt] += lp;
    };

    // PV of one rowtile from tile Vt
    auto pv = [&](int rt, const short* Vt) {
#pragma unroll
        for (int kk = 0; kk < 2; ++kk) {
            short8 aP = *reinterpret_cast<const short8*>(
                &Pt[w][rt * 16 + c][(kk * 32 + g * 8) ^ swz8]);
            __builtin_amdgcn_s_setprio(1);
#pragma unroll
            for (int n = 0; n < 4; ++n) {
                short8 bV = *reinterpret_cast<const short8*>(
                    &Vt[(n * 16 + c) * 64 + ((kk * 32 + g * 8) ^ swz8)]);
                acc[rt][n] = __builtin_amdgcn_mfma_f32_16x16x32_bf16(
                    aP, bV, acc[rt][n], 0, 0, 0);
            }
            __builtin_amdgcn_s_setprio(0);
        }
    };

    // ---- prologue: stage 0,1; compute QK(0)
    stage(0, 0);
    stage(1, 1);
    asm volatile("s_waitcnt vmcnt(2)" ::: "memory");   // stage(0) done
    __builtin_amdgcn_s_barrier();                      // visible to all waves
    __builtin_amdgcn_sched_barrier(0);

    f32x4 sA[4], sB[4];
    qk(Kb[0], bQ[0], sA);
    qk(Kb[0], bQ[1], sB);

    for (int kt = 0; kt < NKT; ++kt) {
        __builtin_amdgcn_s_barrier();                  // safety: bufs(kt-1) consumed by all
        if (kt + 2 < NKT) {
            stage((kt + 2) % 3, kt + 2);
            asm volatile("s_waitcnt vmcnt(2)" ::: "memory");  // stage(kt+1) done (own)
        } else {
            asm volatile("s_waitcnt vmcnt(0)" ::: "memory");
        }
        __builtin_amdgcn_s_barrier();                  // visibility: stage(kt+1) landed
        __builtin_amdgcn_sched_barrier(0);

        const short* Ktn = Kb[(kt + 1) % 3];
        const short* Vt  = Vb[kt % 3];
        const int k0 = kt * KT;

        softmax(0, mrow0, k0, sA);                     // frees sA
        if (kt + 1 < NKT) qk(Ktn, bQ[0], sA);          // QK(kt+1,rt0) ∥ softmax(rt1) VALU
        softmax(1, mrow1, k0, sB);                     // frees sB
        pv(0, Vt);                                     // PV(kt,rt0)
        if (kt + 1 < NKT) qk(Ktn, bQ[1], sB);          // QK(kt+1,rt1)
        pv(1, Vt);                                     // PV(kt,rt1)
    }

    // ---- epilogue: single cross-lane reduce of denominator, normalize, store
#pragma unroll
    for (int rt = 0; rt < 2; ++rt) {
        float l = lR[rt];
        l += __shfl_xor(l, 16);
        l += __shfl_xor(l, 32);        // full denom for q-row (rt,c)
        const float linv = 1.0f / l;
        float ld[4];
        ld[0] = __shfl(linv, 4 * g + 0);
        ld[1] = __shfl(linv, 4 * g + 1);
        ld[2] = __shfl(linv, 4 * g + 2);
        ld[3] = __shfl(linv, 4 * g + 3);
#pragma unroll
        for (int r = 0; r < 4; ++r) {
            float* op = O + (bhS + qw + rt * 16 + 4 * g + r) * D + c;
#pragma unroll
            for (int n = 0; n < 4; ++n) op[n * 16] = acc[rt][n][r] * ld[r];
        }
    }
}

// ---- fallback (ws too small): known-correct f32 kernel
constexpr int FQT = 256, FKT = 64, FSUB = 16;
__global__ __launch_bounds__(FQT)
void attn_f32(const float* __restrict__ Q, const float* __restrict__ K,
              const float* __restrict__ V, const float* __restrict__ M,
              float* __restrict__ O)
{
    __shared__ float Kt[FKT][D];
    __shared__ float Vt[FKT][D];
    const int tid = threadIdx.x;
    const int bh = blockIdx.x / (S / FQT);
    const int qrow = (blockIdx.x % (S / FQT)) * FQT + tid;
    const float* qp = Q + ((size_t)bh * S + qrow) * D;
    const float* mp = M + (size_t)qrow * S;
    const float* kb = K + (size_t)bh * S * D;
    const float* vb = V + (size_t)bh * S * D;
    float qv[D];
#pragma unroll
    for (int d = 0; d < D; d += 4) {
        float4 t = *reinterpret_cast<const float4*>(qp + d);
        qv[d] = t.x * 0.125f; qv[d+1] = t.y * 0.125f; qv[d+2] = t.z * 0.125f; qv[d+3] = t.w * 0.125f;
    }
    float acc[D];
#pragma unroll
    for (int d = 0; d < D; ++d) acc[d] = 0.f;
    float mrun = -1e30f, lrun = 0.f;
    for (int k0 = 0; k0 < S; k0 += FKT) {
        __syncthreads();
        const float4* ks = reinterpret_cast<const float4*>(kb + (size_t)k0 * D);
        const float4* vs = reinterpret_cast<const float4*>(vb + (size_t)k0 * D);
        float4* kd = reinterpret_cast<float4*>(&Kt[0][0]);
        float4* vd = reinterpret_cast<float4*>(&Vt[0][0]);
#pragma unroll
        for (int i = 0; i < (FKT * D / 4) / FQT; ++i) {
            kd[tid + FQT * i] = ks[tid + FQT * i];
            vd[tid + FQT * i] = vs[tid + FQT * i];
        }
        __syncthreads();
        for (int j0 = 0; j0 < FKT; j0 += FSUB) {
            float mk[FSUB];
#pragma unroll
            for (int i = 0; i < FSUB; i += 4) {
                float4 t = *reinterpret_cast<const float4*>(mp + k0 + j0 + i);
                mk[i] = t.x; mk[i+1] = t.y; mk[i+2] = t.z; mk[i+3] = t.w;
            }
            float sx[FSUB];
#pragma unroll
            for (int j = 0; j < FSUB; ++j) sx[j] = 0.f;
#pragma unroll
            for (int d = 0; d < D; d += 4)
#pragma unroll
                for (int j = 0; j < FSUB; ++j) {
                    float4 kv = *reinterpret_cast<const float4*>(&Kt[j0 + j][d]);
                    sx[j] = fmaf(qv[d], kv.x, sx[j]);
                    sx[j] = fmaf(qv[d+1], kv.y, sx[j]);
                    sx[j] = fmaf(qv[d+2], kv.z, sx[j]);
                    sx[j] = fmaf(qv[d+3], kv.w, sx[j]);
                }
            float cmax = -1e30f;
#pragma unroll
            for (int j = 0; j < FSUB; ++j) { sx[j] *= mk[j]; cmax = fmaxf(cmax, sx[j]); }
            if (cmax > mrun) {
                float r = __expf(mrun - cmax);
                mrun = cmax; lrun *= r;
#pragma unroll
                for (int d = 0; d < D; ++d) acc[d] *= r;
            }
#pragma unroll
            for (int j = 0; j < FSUB; ++j) {
                float p = __expf(sx[j] - mrun);
                lrun += p;
#pragma unroll
                for (int d = 0; d < D; d += 4) {
                    float4 vv = *reinterpret_cast<const float4*>(&Vt[j0 + j][d]);
                    acc[d] = fmaf(p, vv.x, acc[d]);
                    acc[d+1] = fmaf(p, vv.y, acc[d+1]);
                    acc[d+2] = fmaf(p, vv.z, acc[d+2]);
                    acc[d+3] = fmaf(p, vv.w, acc[d+3]);
                }
            }
        }
    }
    const float invl = 1.0f / lrun;
    float* op = O + ((size_t)bh * S + qrow) * D;
#pragma unroll
    for (int d = 0; d < D; d += 4) {
        float4 t;
        t.x = acc[d] * invl; t.y = acc[d+1] * invl; t.z = acc[d+2] * invl; t.w = acc[d+3] * invl;
        *reinterpret_cast<float4*>(op + d) = t;
    }
}

extern "C" void kernel_launch(void* const* d_in, const int* in_sizes, int n_in,
                              void* d_out, int out_size, void* d_ws, size_t ws_size,
                              hipStream_t stream) {
    const float* q = (const float*)d_in[0];
    const float* k = (const float*)d_in[1];
    const float* v = (const float*)d_in[2];
    const float* m = (const float*)d_in[3];
    float* out = (float*)d_out;
    if (ws_size >= WS_NEED) {
        short* kimg = (short*)d_ws;
        short* vimg = kimg + IMG_SH;
        conv_kv<<<dim3(2 * NBH * NKT), dim3(256), 0, stream>>>(k, v, kimg, vimg);
        attn_img<<<dim3(NBH * NQT), dim3(512), 0, stream>>>(q, m, kimg, vimg, out);
    } else {
        attn_f32<<<dim3(NBH * (S / FQT)), dim3(256), 0, stream>>>(q, k, v, m, out);
    }
}

// Round 18
// 180.078 us; speedup vs baseline: 1.1549x; 1.1549x over previous
//
#include <hip/hip_runtime.h>
#include <hip/hip_bf16.h>

// R18: 32x32 swapped-QK (S^T = K·Q^T) with IN-REGISTER P (T12 structure):
// P-row is lane-local after 32x32 QK -> softmax has zero cross-lane, and P
// feeds PV's A operand via one shfl_xor(32) exchange per k16-step. Pt LDS
// eliminated (DS ops 36 -> 16 per round/wave; P write->lgkm->read chain gone).
// PV via mfma_32x32x16 (bV 8 b128/round, was 16). LDS 48KB (K/V 3-buf only),
// R16 counted-vmcnt sync verbatim. 8-wave blocks, 32 q-rows/wave.
// exp2-native fixed-max softmax (scores bounded -> m=0, exact).
// bf16 tile images pre-swizzled in ws. B=4 H=16 S=2048 D=64, f32 in/out.

typedef __attribute__((ext_vector_type(4)))  float  f32x4;
typedef __attribute__((ext_vector_type(16))) float  f32x16;
typedef __attribute__((ext_vector_type(8)))  short  short8;
typedef __attribute__((ext_vector_type(4)))  int    int4v;

constexpr int S = 2048, D = 64;
constexpr int NBH = 64;
constexpr int QBLK = 256, KT = 64;
constexpr int NQT = S / QBLK;      // 8
constexpr int NKT = S / KT;        // 32
constexpr float SCALE = 0.125f * 1.44269504088896340736f;  // (1/T)*log2(e)
constexpr size_t TILE_SH = (size_t)KT * D;                 // 4096 shorts (8KB) per tile
constexpr size_t IMG_SH  = (size_t)NBH * NKT * TILE_SH;
constexpr size_t WS_NEED = 2 * IMG_SH * sizeof(short);     // 33.55 MB

__device__ inline unsigned short bfb(float x) {
    union { __hip_bfloat16 h; unsigned short u; } cv;
    cv.h = __float2bfloat16(x);
    return cv.u;
}

__device__ inline float fexp2(float x) {   // native v_exp_f32 (exp2)
#if __has_builtin(__builtin_amdgcn_exp2f)
    return __builtin_amdgcn_exp2f(x);
#else
    return __expf(x * 0.6931471805599453f);
#endif
}

__device__ inline void gload16(const short* g, short* l) {
    auto gp = (const __attribute__((address_space(1))) int*)g;
    auto lp = (__attribute__((address_space(3))) int*)l;
    __builtin_amdgcn_global_load_lds(gp, lp, 16, 0, 0);
}

// ---- merged pre-pass (64-key tiles, 64-wide rows) — unchanged.
// blocks [0, NBH*NKT):        K -> swizzled bf16 tile image [key][d^8*(key&7)]
// blocks [NBH*NKT, 2*NBH*NKT): V -> transposed swizzled image [d][key^8*(d&7)]
__global__ __launch_bounds__(256)
void conv_kv(const float* __restrict__ K, const float* __restrict__ V,
             short* __restrict__ Kimg, short* __restrict__ Vimg) {
    const int t = threadIdx.x;
    const int nt = NBH * NKT;
    if (blockIdx.x < nt) {
        const float* src = K + (size_t)blockIdx.x * TILE_SH;
        short* dst = Kimg + (size_t)blockIdx.x * TILE_SH;
        const int row = t >> 2, c16 = (t & 3) * 16;
        const int swz = (row & 7) << 3;
        float4 f0 = *reinterpret_cast<const float4*>(src + row * D + c16 + 0);
        float4 f1 = *reinterpret_cast<const float4*>(src + row * D + c16 + 4);
        float4 f2 = *reinterpret_cast<const float4*>(src + row * D + c16 + 8);
        float4 f3 = *reinterpret_cast<const float4*>(src + row * D + c16 + 12);
        short8 a, b;
        a[0]=bfb(f0.x); a[1]=bfb(f0.y); a[2]=bfb(f0.z); a[3]=bfb(f0.w);
        a[4]=bfb(f1.x); a[5]=bfb(f1.y); a[6]=bfb(f1.z); a[7]=bfb(f1.w);
        b[0]=bfb(f2.x); b[1]=bfb(f2.y); b[2]=bfb(f2.z); b[3]=bfb(f2.w);
        b[4]=bfb(f3.x); b[5]=bfb(f3.y); b[6]=bfb(f3.z); b[7]=bfb(f3.w);
        *reinterpret_cast<short8*>(dst + row * 64 + (c16 ^ swz)) = a;
        *reinterpret_cast<short8*>(dst + row * 64 + ((c16 + 8) ^ swz)) = b;
    } else {
        __shared__ float tl[64][65];
        const int blk = blockIdx.x - nt;
        const float* src = V + (size_t)blk * TILE_SH;
        short* dst = Vimg + (size_t)blk * TILE_SH;
        const int row = t >> 2, c16 = (t & 3) * 16;
        {
            float4 f0 = *reinterpret_cast<const float4*>(src + row * D + c16 + 0);
            float4 f1 = *reinterpret_cast<const float4*>(src + row * D + c16 + 4);
            float4 f2 = *reinterpret_cast<const float4*>(src + row * D + c16 + 8);
            float4 f3 = *reinterpret_cast<const float4*>(src + row * D + c16 + 12);
            tl[row][c16+0]=f0.x;  tl[row][c16+1]=f0.y;  tl[row][c16+2]=f0.z;  tl[row][c16+3]=f0.w;
            tl[row][c16+4]=f1.x;  tl[row][c16+5]=f1.y;  tl[row][c16+6]=f1.z;  tl[row][c16+7]=f1.w;
            tl[row][c16+8]=f2.x;  tl[row][c16+9]=f2.y;  tl[row][c16+10]=f2.z; tl[row][c16+11]=f2.w;
            tl[row][c16+12]=f3.x; tl[row][c16+13]=f3.y; tl[row][c16+14]=f3.z; tl[row][c16+15]=f3.w;
        }
        __syncthreads();
        const int d = t >> 2, k16 = (t & 3) * 16;
        const int swz = (d & 7) << 3;
        float vv[16];
#pragma unroll
        for (int j = 0; j < 16; ++j) vv[j] = tl[k16 + j][d];
        short8 a, b;
#pragma unroll
        for (int j = 0; j < 8; ++j) { a[j] = bfb(vv[j]); b[j] = bfb(vv[j + 8]); }
        *reinterpret_cast<short8*>(dst + d * 64 + (k16 ^ swz)) = a;
        *reinterpret_cast<short8*>(dst + d * 64 + ((k16 + 8) ^ swz)) = b;
    }
}

// ---- main attention kernel: 8 waves x 32 q-rows each, 32x32 MFMA, no Pt
__global__ __launch_bounds__(512)
void attn_img(const float* __restrict__ Q, const float* __restrict__ M,
              const short* __restrict__ Kimg, const short* __restrict__ Vimg,
              float* __restrict__ O)
{
    __shared__ short Kb[3][4096];     // 24 KB triple buffer
    __shared__ short Vb[3][4096];     // 24 KB
    // total 48 KB

    const int tid  = threadIdx.x;
    const int w    = tid >> 6;        // 0..7
    const int lane = tid & 63;
    const int c32  = lane & 31;
    const int lo   = lane >> 5;       // 0/1
    const int zr   = (c32 & 7) << 3;  // row-swizzle for rows c32 and c32+32

    const int bid = blockIdx.x;
    const int bh  = bid >> 3;         // consecutive bids share bh -> L2 reuse
    const int qt  = bid & 7;
    const int qw  = qt * QBLK + w * 32;

    const size_t bhS = (size_t)bh * S;
    const size_t bhT = (size_t)bh * NKT;

    // ---- Q fragments (B operand of 32x32x16): lane holds Q[qw+c32][ks*16+8lo+0..7]
    short8 bQ[4];
    {
        const float* qp = Q + (bhS + qw + c32) * D;
#pragma unroll
        for (int ks = 0; ks < 4; ++ks) {
            const float* q8 = qp + ks * 16 + lo * 8;
            float4 a = *reinterpret_cast<const float4*>(q8);
            float4 b = *reinterpret_cast<const float4*>(q8 + 4);
            short8 r;
            r[0] = bfb(a.x * SCALE); r[1] = bfb(a.y * SCALE);
            r[2] = bfb(a.z * SCALE); r[3] = bfb(a.w * SCALE);
            r[4] = bfb(b.x * SCALE); r[5] = bfb(b.y * SCALE);
            r[6] = bfb(b.z * SCALE); r[7] = bfb(b.w * SCALE);
            bQ[ks] = r;
        }
    }

    const float* mrow = M + (size_t)(qw + c32) * S;   // this lane's q-row mask

    f32x16 acc32[2] = {};             // PV accum: C col=c32 -> d=c32+32n, row=qrow
    float lR = 0.f;                   // partial denominator (this lane's keys)

    // stage: 512 threads x 16B = full 8KB tile in ONE pass per tensor
    auto stage = [&](int buf, int kt) {
        const short* ks = Kimg + (bhT + kt) * TILE_SH + tid * 8;
        const short* vs = Vimg + (bhT + kt) * TILE_SH + tid * 8;
        gload16(ks, &Kb[buf][tid * 8]);
        gload16(vs, &Vb[buf][tid * 8]);
    };

    stage(0, 0);
    stage(1, 1);

    for (int kt = 0; kt < NKT; ++kt) {
        if (kt == NKT - 1) {
            asm volatile("s_waitcnt vmcnt(0)" ::: "memory");
        } else {
            asm volatile("s_waitcnt vmcnt(2)" ::: "memory");
        }
        __builtin_amdgcn_s_barrier();          // raw barrier, no drain
        __builtin_amdgcn_sched_barrier(0);

        if (kt + 2 < NKT) stage((kt + 2) % 3, kt + 2);

        const short* Kt = Kb[kt % 3];
        const short* Vt = Vb[kt % 3];
        const int k0 = kt * KT;

        // ---- QK^T swapped (32x32x16): sT[sub] = K[32sub..+31] · Q^T
        //      C: col = c32 = qrow, row(reg j) = (j&3)+8*(j>>2)+4*lo = key-in-subtile
        f32x16 sT[2] = {};
        __builtin_amdgcn_s_setprio(1);
#pragma unroll
        for (int ks = 0; ks < 4; ++ks) {
            short8 a0 = *reinterpret_cast<const short8*>(
                &Kt[c32 * 64 + ((ks * 16 + lo * 8) ^ zr)]);
            short8 a1 = *reinterpret_cast<const short8*>(
                &Kt[(c32 + 32) * 64 + ((ks * 16 + lo * 8) ^ zr)]);
            sT[0] = __builtin_amdgcn_mfma_f32_32x32x16_bf16(a0, bQ[ks], sT[0], 0, 0, 0);
            sT[1] = __builtin_amdgcn_mfma_f32_32x32x16_bf16(a1, bQ[ks], sT[1], 0, 0, 0);
        }
        __builtin_amdgcn_s_setprio(0);

        // ---- softmax (fixed max 0, exact; lane-local q-row) + bf16 pack in regs
        // quad (sub,q): keys 32sub + 8q + 4lo + 0..3  ->  prx/pry u32 bf16-pairs
        unsigned prx[2][4], pry[2][4];
        float lp = 0.f;
#pragma unroll
        for (int sub = 0; sub < 2; ++sub) {
#pragma unroll
            for (int q = 0; q < 4; ++q) {
                float4 mk = *reinterpret_cast<const float4*>(
                    mrow + k0 + 32 * sub + 8 * q + 4 * lo);
                float e0 = fexp2(sT[sub][4 * q + 0] * mk.x);
                float e1 = fexp2(sT[sub][4 * q + 1] * mk.y);
                float e2 = fexp2(sT[sub][4 * q + 2] * mk.z);
                float e3 = fexp2(sT[sub][4 * q + 3] * mk.w);
                lp += (e0 + e1) + (e2 + e3);
                prx[sub][q] = (unsigned)bfb(e0) | ((unsigned)bfb(e1) << 16);
                pry[sub][q] = (unsigned)bfb(e2) | ((unsigned)bfb(e3) << 16);
            }
        }
        lR += lp;

        // ---- PV (32x32x16): A = P (rows = qrow, k = 16 keys), in-register.
        // A-frag(kk): keys 16*(kk&1)+8lo+0..7 of sub=kk>>1; exchange with lane^32.
#pragma unroll
        for (int kk = 0; kk < 4; ++kk) {
            const int sub = kk >> 1, b = kk & 1;
            const unsigned ux = prx[sub][2 * b],     uy = pry[sub][2 * b];
            const unsigned vx = prx[sub][2 * b + 1], vy = pry[sub][2 * b + 1];
            const unsigned sx = lo ? ux : vx, sy = lo ? uy : vy;  // send what partner needs
            const unsigned rx = __shfl_xor(sx, 32), ry = __shfl_xor(sy, 32);
            int4v f;
            f.x = (int)(lo ? rx : ux);
            f.y = (int)(lo ? ry : uy);
            f.z = (int)(lo ? vx : rx);
            f.w = (int)(lo ? vy : ry);
            short8 aP = *reinterpret_cast<short8*>(&f);
            __builtin_amdgcn_s_setprio(1);
#pragma unroll
            for (int n = 0; n < 2; ++n) {
                const int vr = c32 + 32 * n;          // V^T image row = d
                short8 bV = *reinterpret_cast<const short8*>(
                    &Vt[vr * 64 + ((kk * 16 + lo * 8) ^ zr)]);
                acc32[n] = __builtin_amdgcn_mfma_f32_32x32x16_bf16(aP, bV, acc32[n], 0, 0, 0);
            }
            __builtin_amdgcn_s_setprio(0);
        }
    }

    // ---- epilogue: denom = own + partner(lane^32); normalize, store
    {
        const float l = lR + __shfl_xor(lR, 32);   // full denom for q-row c32
        const float linv = 1.0f / l;
#pragma unroll
        for (int j = 0; j < 16; ++j) {
            const int qrow = (j & 3) + 8 * (j >> 2) + 4 * lo;
            const float ldv = __shfl(linv, qrow);  // lane qrow holds that row's denom
            float* op = O + (bhS + qw + qrow) * D + c32;
            op[0]  = acc32[0][j] * ldv;
            op[32] = acc32[1][j] * ldv;
        }
    }
}

// ---- fallback (ws too small): known-correct f32 kernel
constexpr int FQT = 256, FKT = 64, FSUB = 16;
__global__ __launch_bounds__(FQT)
void attn_f32(const float* __restrict__ Q, const float* __restrict__ K,
              const float* __restrict__ V, const float* __restrict__ M,
              float* __restrict__ O)
{
    __shared__ float Kt[FKT][D];
    __shared__ float Vt[FKT][D];
    const int tid = threadIdx.x;
    const int bh = blockIdx.x / (S / FQT);
    const int qrow = (blockIdx.x % (S / FQT)) * FQT + tid;
    const float* qp = Q + ((size_t)bh * S + qrow) * D;
    const float* mp = M + (size_t)qrow * S;
    const float* kb = K + (size_t)bh * S * D;
    const float* vb = V + (size_t)bh * S * D;
    float qv[D];
#pragma unroll
    for (int d = 0; d < D; d += 4) {
        float4 t = *reinterpret_cast<const float4*>(qp + d);
        qv[d] = t.x * 0.125f; qv[d+1] = t.y * 0.125f; qv[d+2] = t.z * 0.125f; qv[d+3] = t.w * 0.125f;
    }
    float acc[D];
#pragma unroll
    for (int d = 0; d < D; ++d) acc[d] = 0.f;
    float mrun = -1e30f, lrun = 0.f;
    for (int k0 = 0; k0 < S; k0 += FKT) {
        __syncthreads();
        const float4* ks = reinterpret_cast<const float4*>(kb + (size_t)k0 * D);
        const float4* vs = reinterpret_cast<const float4*>(vb + (size_t)k0 * D);
        float4* kd = reinterpret_cast<float4*>(&Kt[0][0]);
        float4* vd = reinterpret_cast<float4*>(&Vt[0][0]);
#pragma unroll
        for (int i = 0; i < (FKT * D / 4) / FQT; ++i) {
            kd[tid + FQT * i] = ks[tid + FQT * i];
            vd[tid + FQT * i] = vs[tid + FQT * i];
        }
        __syncthreads();
        for (int j0 = 0; j0 < FKT; j0 += FSUB) {
            float mk[FSUB];
#pragma unroll
            for (int i = 0; i < FSUB; i += 4) {
                float4 t = *reinterpret_cast<const float4*>(mp + k0 + j0 + i);
                mk[i] = t.x; mk[i+1] = t.y; mk[i+2] = t.z; mk[i+3] = t.w;
            }
            float sx[FSUB];
#pragma unroll
            for (int j = 0; j < FSUB; ++j) sx[j] = 0.f;
#pragma unroll
            for (int d = 0; d < D; d += 4)
#pragma unroll
                for (int j = 0; j < FSUB; ++j) {
                    float4 kv = *reinterpret_cast<const float4*>(&Kt[j0 + j][d]);
                    sx[j] = fmaf(qv[d], kv.x, sx[j]);
                    sx[j] = fmaf(qv[d+1], kv.y, sx[j]);
                    sx[j] = fmaf(qv[d+2], kv.z, sx[j]);
                    sx[j] = fmaf(qv[d+3], kv.w, sx[j]);
                }
            float cmax = -1e30f;
#pragma unroll
            for (int j = 0; j < FSUB; ++j) { sx[j] *= mk[j]; cmax = fmaxf(cmax, sx[j]); }
            if (cmax > mrun) {
                float r = __expf(mrun - cmax);
                mrun = cmax; lrun *= r;
#pragma unroll
                for (int d = 0; d < D; ++d) acc[d] *= r;
            }
#pragma unroll
            for (int j = 0; j < FSUB; ++j) {
                float p = __expf(sx[j] - mrun);
                lrun += p;
#pragma unroll
                for (int d = 0; d < D; d += 4) {
                    float4 vv = *reinterpret_cast<const float4*>(&Vt[j0 + j][d]);
                    acc[d] = fmaf(p, vv.x, acc[d]);
                    acc[d+1] = fmaf(p, vv.y, acc[d+1]);
                    acc[d+2] = fmaf(p, vv.z, acc[d+2]);
                    acc[d+3] = fmaf(p, vv.w, acc[d+3]);
                }
            }
        }
    }
    const float invl = 1.0f / lrun;
    float* op = O + ((size_t)bh * S + qrow) * D;
#pragma unroll
    for (int d = 0; d < D; d += 4) {
        float4 t;
        t.x = acc[d] * invl; t.y = acc[d+1] * invl; t.z = acc[d+2] * invl; t.w = acc[d+3] * invl;
        *reinterpret_cast<float4*>(op + d) = t;
    }
}

extern "C" void kernel_launch(void* const* d_in, const int* in_sizes, int n_in,
                              void* d_out, int out_size, void* d_ws, size_t ws_size,
                              hipStream_t stream) {
    const float* q = (const float*)d_in[0];
    const float* k = (const float*)d_in[1];
    const float* v = (const float*)d_in[2];
    const float* m = (const float*)d_in[3];
    float* out = (float*)d_out;
    if (ws_size >= WS_NEED) {
        short* kimg = (short*)d_ws;
        short* vimg = kimg + IMG_SH;
        conv_kv<<<dim3(2 * NBH * NKT), dim3(256), 0, stream>>>(k, v, kimg, vimg);
        attn_img<<<dim3(NBH * NQT), dim3(512), 0, stream>>>(q, m, kimg, vimg, out);
    } else {
        attn_f32<<<dim3(NBH * (S / FQT)), dim3(256), 0, stream>>>(q, k, v, m, out);
    }
}